// Round 1
// baseline (1004.400 us; speedup 1.0000x reference)
//
#include <hip/hip_runtime.h>
#include <math.h>

// ---------- helpers ----------
__device__ __forceinline__ unsigned enc_f(float f) {
    unsigned u = __float_as_uint(f);
    return (u & 0x80000000u) ? ~u : (u | 0x80000000u);
}
__device__ __forceinline__ float dec_f(unsigned u) {
    unsigned v = (u & 0x80000000u) ? (u & 0x7FFFFFFFu) : ~u;
    return __uint_as_float(v);
}

// ---------- generic fp32 tiled GEMM: C[M,N] = A[M,K] @ B[K,N] ----------
template<int BM, int BN, int BK>
__global__ __launch_bounds__(256) void gemm_f32(const float* __restrict__ A,
        const float* __restrict__ B, float* __restrict__ C,
        int M, int N, int K) {
    __shared__ float As[BK][BM + 1];
    __shared__ float Bs[BK][BN + 1];
    int tid = threadIdx.x;
    int tx = tid & 15;   // N dir (16)
    int ty = tid >> 4;   // M dir (16)
    int row0 = blockIdx.y * BM;
    int col0 = blockIdx.x * BN;
    float acc[4][4] = {};
    for (int k0 = 0; k0 < K; k0 += BK) {
        #pragma unroll
        for (int i = 0; i < (BM * BK) / 256; ++i) {
            int idx = tid + i * 256;
            int r = idx / BK, c = idx % BK;
            int gr = row0 + r;
            float v = 0.f;
            if (gr < M) v = A[(long)gr * K + k0 + c];
            As[c][r] = v;
        }
        #pragma unroll
        for (int i = 0; i < (BK * BN) / 256; ++i) {
            int idx = tid + i * 256;
            int r = idx / BN, c = idx % BN;
            int gc = col0 + c;
            float v = 0.f;
            if (gc < N) v = B[(long)(k0 + r) * N + gc];
            Bs[r][c] = v;
        }
        __syncthreads();
        #pragma unroll
        for (int k = 0; k < BK; ++k) {
            float a[4], b[4];
            #pragma unroll
            for (int i = 0; i < 4; ++i) a[i] = As[k][ty * 4 + i];
            #pragma unroll
            for (int j = 0; j < 4; ++j) b[j] = Bs[k][tx * 4 + j];
            #pragma unroll
            for (int i = 0; i < 4; ++i)
                #pragma unroll
                for (int j = 0; j < 4; ++j)
                    acc[i][j] += a[i] * b[j];
        }
        __syncthreads();
    }
    #pragma unroll
    for (int i = 0; i < 4; ++i) {
        int gr = row0 + ty * 4 + i;
        if (gr >= M) continue;
        #pragma unroll
        for (int j = 0; j < 4; ++j) {
            int gc = col0 + tx * 4 + j;
            if (gc < N) C[(long)gr * N + gc] = acc[i][j];
        }
    }
}

// ---------- attention projections ----------
// layer 1: xp [N,256] (=[N,4,64]); att vectors [4,64] flat (t = h*64+c)
__global__ __launch_bounds__(256) void att_proj_h4(const float* __restrict__ xp,
        const float* __restrict__ att_s, const float* __restrict__ att_d,
        float* __restrict__ a_s, float* __restrict__ a_d, int N) {
    int n = blockIdx.x;
    int t = threadIdx.x;
    float p = xp[(long)n * 256 + t];
    float vs = p * att_s[t];
    float vd = p * att_d[t];
    #pragma unroll
    for (int off = 32; off; off >>= 1) {
        vs += __shfl_down(vs, off);
        vd += __shfl_down(vd, off);
    }
    if ((t & 63) == 0) {
        int h = t >> 6;
        a_s[n * 4 + h] = vs;
        a_d[n * 4 + h] = vd;
    }
}

// layer 2: xp [N,32], att [32]; block of 256 handles 8 nodes
__global__ __launch_bounds__(256) void att_proj_h1(const float* __restrict__ xp,
        const float* __restrict__ att_s, const float* __restrict__ att_d,
        float* __restrict__ a_s, float* __restrict__ a_d, int N) {
    int t = threadIdx.x;
    int n = blockIdx.x * 8 + (t >> 5);
    if (n >= N) return;
    int c = t & 31;
    float p = xp[(long)n * 32 + c];
    float vs = p * att_s[c];
    float vd = p * att_d[c];
    #pragma unroll
    for (int off = 16; off; off >>= 1) {
        vs += __shfl_xor(vs, off, 32);
        vd += __shfl_xor(vd, off, 32);
    }
    if (c == 0) { a_s[n] = vs; a_d[n] = vd; }
}

// ---------- edge softmax pipeline ----------
template<int H>
__global__ __launch_bounds__(256) void edge_logit_max(const int* __restrict__ ei,
        int E, int Etot, const float* __restrict__ a_s, const float* __restrict__ a_d,
        float* __restrict__ alpha, unsigned* __restrict__ menc) {
    int i = blockIdx.x * 256 + threadIdx.x;
    int tot = Etot * H;
    if (i >= tot) return;
    int e = i / H, h = i - e * H;
    int s, d;
    if (e < E) { s = ei[e]; d = ei[E + e]; } else { s = e - E; d = s; }
    float a = a_s[s * H + h] + a_d[d * H + h];
    a = a > 0.f ? a : 0.2f * a;           // leaky_relu slope 0.2
    alpha[i] = a;
    atomicMax(&menc[d * H + h], enc_f(a));
}

template<int H>
__global__ __launch_bounds__(256) void edge_exp_sum(const int* __restrict__ ei,
        int E, int Etot, float* __restrict__ alpha, const unsigned* __restrict__ menc,
        float* __restrict__ ssum) {
    int i = blockIdx.x * 256 + threadIdx.x;
    int tot = Etot * H;
    if (i >= tot) return;
    int e = i / H, h = i - e * H;
    int d = (e < E) ? ei[E + e] : e - E;
    float m = dec_f(menc[d * H + h]);
    float ex = expf(alpha[i] - m);
    alpha[i] = ex;
    atomicAdd(&ssum[d * H + h], ex);
}

template<int H>
__global__ __launch_bounds__(256) void edge_coeff(const int* __restrict__ ei,
        int E, int Etot, float* __restrict__ alpha, const float* __restrict__ ssum) {
    int i = blockIdx.x * 256 + threadIdx.x;
    int tot = Etot * H;
    if (i >= tot) return;
    int e = i / H, h = i - e * H;
    int d = (e < E) ? ei[E + e] : e - E;
    alpha[i] = alpha[i] / (ssum[d * H + h] + 1e-16f);
}

// ---------- aggregation ----------
// layer 1: 256 channels per edge (4 heads x 64); one block per edge
__global__ __launch_bounds__(256) void edge_agg_256(const int* __restrict__ ei,
        int E, int Etot, const float* __restrict__ coeff, const float* __restrict__ xp,
        float* __restrict__ out) {
    int e = blockIdx.x;
    if (e >= Etot) return;
    int t = threadIdx.x;
    int s, d;
    if (e < E) { s = ei[e]; d = ei[E + e]; } else { s = e - E; d = s; }
    float c = coeff[e * 4 + (t >> 6)];
    atomicAdd(&out[(long)d * 256 + t], c * xp[(long)s * 256 + t]);
}

// layer 2: 32 channels per edge; block of 256 handles 8 edges
__global__ __launch_bounds__(256) void edge_agg_32(const int* __restrict__ ei,
        int E, int Etot, const float* __restrict__ coeff, const float* __restrict__ xp,
        float* __restrict__ out) {
    int t = threadIdx.x;
    int e = blockIdx.x * 8 + (t >> 5);
    if (e >= Etot) return;
    int c = t & 31;
    int s, d;
    if (e < E) { s = ei[e]; d = ei[E + e]; } else { s = e - E; d = s; }
    atomicAdd(&out[(long)d * 32 + c], coeff[e] * xp[(long)s * 32 + c]);
}

// ---------- epilogues ----------
__global__ __launch_bounds__(256) void bias_elu(float* __restrict__ h,
        const float* __restrict__ b, int N) {
    int n = blockIdx.x;
    int t = threadIdx.x;
    long idx = (long)n * 256 + t;
    float v = h[idx] + b[t];
    h[idx] = v > 0.f ? v : expm1f(v);
}

__global__ __launch_bounds__(256) void final_softmax(const float* __restrict__ agg,
        const float* __restrict__ b, float* __restrict__ out, int N) {
    int t = threadIdx.x;
    int n = blockIdx.x * 8 + (t >> 5);
    if (n >= N) return;
    int c = t & 31;
    float v = agg[(long)n * 32 + c] + b[c];
    float m = v;
    #pragma unroll
    for (int off = 16; off; off >>= 1) m = fmaxf(m, __shfl_xor(m, off, 32));
    float ex = expf(v - m);
    float s = ex;
    #pragma unroll
    for (int off = 16; off; off >>= 1) s += __shfl_xor(s, off, 32);
    out[(long)n * 32 + c] = ex / s;
}

// ---------- host ----------
extern "C" void kernel_launch(void* const* d_in, const int* in_sizes, int n_in,
                              void* d_out, int out_size, void* d_ws, size_t ws_size,
                              hipStream_t stream) {
    const float* x   = (const float*)d_in[0];
    const int*   ei  = (const int*)d_in[1];
    const float* W1  = (const float*)d_in[2];
    const float* as1 = (const float*)d_in[3];
    const float* ad1 = (const float*)d_in[4];
    const float* b1  = (const float*)d_in[5];
    const float* W2  = (const float*)d_in[6];
    const float* as2 = (const float*)d_in[7];
    const float* ad2 = (const float*)d_in[8];
    const float* b2  = (const float*)d_in[9];
    float* out = (float*)d_out;

    const int N = in_sizes[0] / 128;     // 50000
    const int E = in_sizes[1] / 2;       // 640000
    const int Etot = E + N;              // self-loops appended

    // workspace layout (floats)
    float* ws = (float*)d_ws;
    float*    xp1    = ws;                       // N*256
    float*    h      = xp1 + (long)N * 256;      // N*256
    float*    a_s1   = h + (long)N * 256;        // N*4
    float*    a_d1   = a_s1 + N * 4;             // N*4
    unsigned* m1     = (unsigned*)(a_d1 + N * 4);// N*4
    float*    s1     = (float*)m1 + N * 4;       // N*4
    float*    alpha1 = s1 + N * 4;               // Etot*4
    float*    a_s2   = alpha1 + (long)Etot * 4;  // N
    float*    a_d2   = a_s2 + N;                 // N
    unsigned* m2     = (unsigned*)(a_d2 + N);    // N
    float*    s2     = (float*)m2 + N;           // N
    float*    alpha2 = s2 + N;                   // Etot
    float*    agg2   = alpha2 + Etot;            // N*32
    float*    xp2    = xp1;                      // reuse: xp1 dead after layer-1 agg

    // zero-init accumulators (every call; ws is poisoned once, never restored)
    hipMemsetAsync(m1, 0, (size_t)N * 4 * sizeof(unsigned), stream);
    hipMemsetAsync(s1, 0, (size_t)N * 4 * sizeof(float), stream);
    hipMemsetAsync(h,  0, (size_t)N * 256 * sizeof(float), stream);
    hipMemsetAsync(m2, 0, (size_t)N * sizeof(unsigned), stream);
    hipMemsetAsync(s2, 0, (size_t)N * sizeof(float), stream);
    hipMemsetAsync(agg2, 0, (size_t)N * 32 * sizeof(float), stream);

    // ---- layer 1 ----
    {
        dim3 g(256 / 64, (N + 63) / 64);
        gemm_f32<64, 64, 16><<<g, 256, 0, stream>>>(x, W1, xp1, N, 256, 128);
    }
    att_proj_h4<<<N, 256, 0, stream>>>(xp1, as1, ad1, a_s1, a_d1, N);
    {
        int tot = Etot * 4;
        int nb = (tot + 255) / 256;
        edge_logit_max<4><<<nb, 256, 0, stream>>>(ei, E, Etot, a_s1, a_d1, alpha1, m1);
        edge_exp_sum<4><<<nb, 256, 0, stream>>>(ei, E, Etot, alpha1, m1, s1);
        edge_coeff<4><<<nb, 256, 0, stream>>>(ei, E, Etot, alpha1, s1);
    }
    edge_agg_256<<<Etot, 256, 0, stream>>>(ei, E, Etot, alpha1, xp1, h);
    bias_elu<<<N, 256, 0, stream>>>(h, b1, N);

    // ---- layer 2 ----
    {
        dim3 g(1, (N + 63) / 64);
        gemm_f32<64, 64, 16><<<g, 256, 0, stream>>>(h, W2, xp2, N, 32, 256);
    }
    att_proj_h1<<<(N + 7) / 8, 256, 0, stream>>>(xp2, as2, ad2, a_s2, a_d2, N);
    {
        int tot = Etot;
        int nb = (tot + 255) / 256;
        edge_logit_max<1><<<nb, 256, 0, stream>>>(ei, E, Etot, a_s2, a_d2, alpha2, m2);
        edge_exp_sum<1><<<nb, 256, 0, stream>>>(ei, E, Etot, alpha2, m2, s2);
        edge_coeff<1><<<nb, 256, 0, stream>>>(ei, E, Etot, alpha2, s2);
    }
    edge_agg_32<<<(Etot + 7) / 8, 256, 0, stream>>>(ei, E, Etot, alpha2, xp2, agg2);
    final_softmax<<<(N + 7) / 8, 256, 0, stream>>>(agg2, b2, out, N);
}

// Round 2
// 611.641 us; speedup vs baseline: 1.6421x; 1.6421x over previous
//
#include <hip/hip_runtime.h>
#include <math.h>

#define NEG_SENT -1e30f

// ---------- generic fp32 tiled GEMM: C[M,N] = A[M,K] @ B[K,N] ----------
template<int BM, int BN, int BK>
__global__ __launch_bounds__(256) void gemm_f32(const float* __restrict__ A,
        const float* __restrict__ B, float* __restrict__ C,
        int M, int N, int K) {
    __shared__ float As[BK][BM + 1];
    __shared__ float Bs[BK][BN + 1];
    int tid = threadIdx.x;
    int tx = tid & 15;   // N dir (16)
    int ty = tid >> 4;   // M dir (16)
    int row0 = blockIdx.y * BM;
    int col0 = blockIdx.x * BN;
    float acc[4][4] = {};
    for (int k0 = 0; k0 < K; k0 += BK) {
        #pragma unroll
        for (int i = 0; i < (BM * BK) / 256; ++i) {
            int idx = tid + i * 256;
            int r = idx / BK, c = idx % BK;
            int gr = row0 + r;
            float v = 0.f;
            if (gr < M) v = A[(long)gr * K + k0 + c];
            As[c][r] = v;
        }
        #pragma unroll
        for (int i = 0; i < (BK * BN) / 256; ++i) {
            int idx = tid + i * 256;
            int r = idx / BN, c = idx % BN;
            int gc = col0 + c;
            float v = 0.f;
            if (gc < N) v = B[(long)(k0 + r) * N + gc];
            Bs[r][c] = v;
        }
        __syncthreads();
        #pragma unroll
        for (int k = 0; k < BK; ++k) {
            float a[4], b[4];
            #pragma unroll
            for (int i = 0; i < 4; ++i) a[i] = As[k][ty * 4 + i];
            #pragma unroll
            for (int j = 0; j < 4; ++j) b[j] = Bs[k][tx * 4 + j];
            #pragma unroll
            for (int i = 0; i < 4; ++i)
                #pragma unroll
                for (int j = 0; j < 4; ++j)
                    acc[i][j] += a[i] * b[j];
        }
        __syncthreads();
    }
    #pragma unroll
    for (int i = 0; i < 4; ++i) {
        int gr = row0 + ty * 4 + i;
        if (gr >= M) continue;
        #pragma unroll
        for (int j = 0; j < 4; ++j) {
            int gc = col0 + tx * 4 + j;
            if (gc < N) C[(long)gr * N + gc] = acc[i][j];
        }
    }
}

// ---------- attention projections ----------
__global__ __launch_bounds__(256) void att_proj_h4(const float* __restrict__ xp,
        const float* __restrict__ att_s, const float* __restrict__ att_d,
        float* __restrict__ a_s, float* __restrict__ a_d, int N) {
    int n = blockIdx.x;
    int t = threadIdx.x;
    float p = xp[(long)n * 256 + t];
    float vs = p * att_s[t];
    float vd = p * att_d[t];
    #pragma unroll
    for (int off = 32; off; off >>= 1) {
        vs += __shfl_down(vs, off);
        vd += __shfl_down(vd, off);
    }
    if ((t & 63) == 0) {
        int h = t >> 6;
        a_s[n * 4 + h] = vs;
        a_d[n * 4 + h] = vd;
    }
}

__global__ __launch_bounds__(256) void att_proj_h1(const float* __restrict__ xp,
        const float* __restrict__ att_s, const float* __restrict__ att_d,
        float* __restrict__ a_s, float* __restrict__ a_d, int N) {
    int t = threadIdx.x;
    int n = blockIdx.x * 8 + (t >> 5);
    if (n >= N) return;
    int c = t & 31;
    float p = xp[(long)n * 32 + c];
    float vs = p * att_s[c];
    float vd = p * att_d[c];
    #pragma unroll
    for (int off = 16; off; off >>= 1) {
        vs += __shfl_xor(vs, off, 32);
        vd += __shfl_xor(vd, off, 32);
    }
    if (c == 0) { a_s[n] = vs; a_d[n] = vd; }
}

// ---------- CSR build ----------
__global__ __launch_bounds__(256) void count_deg(const int* __restrict__ ei,
        int E, int Etot, int* __restrict__ deg) {
    int e = blockIdx.x * 256 + threadIdx.x;
    if (e >= Etot) return;
    int d = (e < E) ? ei[E + e] : e - E;
    atomicAdd(&deg[d], 1);
}

__global__ __launch_bounds__(1024) void scan_deg(const int* __restrict__ deg,
        int* __restrict__ rowptr, int* __restrict__ cursor, int N) {
    __shared__ int part[1024];
    int t = threadIdx.x;
    int chunk = (N + 1023) / 1024;
    int lo = t * chunk;
    int hi = lo + chunk; if (hi > N) hi = N; if (lo > N) lo = N;
    int sum = 0;
    for (int i = lo; i < hi; ++i) sum += deg[i];
    part[t] = sum;
    __syncthreads();
    for (int off = 1; off < 1024; off <<= 1) {
        int v = (t >= off) ? part[t - off] : 0;
        __syncthreads();
        part[t] += v;
        __syncthreads();
    }
    int run = (t > 0) ? part[t - 1] : 0;
    for (int i = lo; i < hi; ++i) {
        rowptr[i] = run;
        cursor[i] = run;
        run += deg[i];
    }
    if (t == 1023) rowptr[N] = part[1023];
}

__global__ __launch_bounds__(256) void scatter_edges(const int* __restrict__ ei,
        int E, int Etot, int* __restrict__ cursor, int* __restrict__ csr_src) {
    int e = blockIdx.x * 256 + threadIdx.x;
    if (e >= Etot) return;
    int s, d;
    if (e < E) { s = ei[e]; d = ei[E + e]; } else { s = e - E; d = s; }
    int pos = atomicAdd(&cursor[d], 1);
    csr_src[pos] = s;
}

// ---------- per-dst softmax stats (flash-style, no atomics) ----------
// merge (m,s) pairs; NEG_SENT sentinel avoids -inf NaN
__device__ __forceinline__ void merge_ms(float& m, float& s, float m2, float s2) {
    float mn = fmaxf(m, m2);
    s = s * expf(m - mn) + s2 * expf(m2 - mn);
    m = mn;
}

// H=4: wave per node; lane = j*4 + h (16 edge slots x 4 heads)
__global__ __launch_bounds__(256) void stats_h4(const int* __restrict__ rowptr,
        const int* __restrict__ csr_src, const float* __restrict__ a_s,
        const float* __restrict__ a_d, float* __restrict__ mout,
        float* __restrict__ isout, int N) {
    int t = threadIdx.x;
    int d = blockIdx.x * 4 + (t >> 6);
    if (d >= N) return;
    int lane = t & 63;
    int h = lane & 3;
    int j0 = lane >> 2;
    int row0 = rowptr[d];
    int deg = rowptr[d + 1] - row0;
    float ad = a_d[d * 4 + h];
    float m = NEG_SENT, s = 0.f;
    for (int j = j0; j < deg; j += 16) {
        int sn = csr_src[row0 + j];
        float l = a_s[sn * 4 + h] + ad;
        l = l > 0.f ? l : 0.2f * l;
        float mn = fmaxf(m, l);
        s = s * expf(m - mn) + expf(l - mn);
        m = mn;
    }
    #pragma unroll
    for (int off = 4; off <= 32; off <<= 1) {
        float m2 = __shfl_xor(m, off);
        float s2 = __shfl_xor(s, off);
        merge_ms(m, s, m2, s2);
    }
    if (j0 == 0) {
        mout[d * 4 + h] = m;
        isout[d * 4 + h] = 1.f / (s + 1e-16f);
    }
}

// H=1: wave per node; lane = edge slot
__global__ __launch_bounds__(256) void stats_h1(const int* __restrict__ rowptr,
        const int* __restrict__ csr_src, const float* __restrict__ a_s,
        const float* __restrict__ a_d, float* __restrict__ mout,
        float* __restrict__ isout, int N) {
    int t = threadIdx.x;
    int d = blockIdx.x * 4 + (t >> 6);
    if (d >= N) return;
    int lane = t & 63;
    int row0 = rowptr[d];
    int deg = rowptr[d + 1] - row0;
    float ad = a_d[d];
    float m = NEG_SENT, s = 0.f;
    for (int j = lane; j < deg; j += 64) {
        int sn = csr_src[row0 + j];
        float l = a_s[sn] + ad;
        l = l > 0.f ? l : 0.2f * l;
        float mn = fmaxf(m, l);
        s = s * expf(m - mn) + expf(l - mn);
        m = mn;
    }
    #pragma unroll
    for (int off = 1; off <= 32; off <<= 1) {
        float m2 = __shfl_xor(m, off);
        float s2 = __shfl_xor(s, off);
        merge_ms(m, s, m2, s2);
    }
    if (lane == 0) {
        mout[d] = m;
        isout[d] = 1.f / (s + 1e-16f);
    }
}

// ---------- gather aggregation ----------
// layer 1: block(256) per dst node, thread = channel; fused bias + ELU
__global__ __launch_bounds__(256) void agg1_gather(const int* __restrict__ rowptr,
        const int* __restrict__ csr_src, const float* __restrict__ a_s,
        const float* __restrict__ a_d, const float* __restrict__ m1,
        const float* __restrict__ is1, const float* __restrict__ xp,
        const float* __restrict__ bias, float* __restrict__ hout, int N) {
    int d = blockIdx.x;
    int t = threadIdx.x;
    int h = t >> 6;
    int row0 = rowptr[d];
    int deg = rowptr[d + 1] - row0;
    float ad = a_d[d * 4 + h];
    float md = m1[d * 4 + h];
    float inv = is1[d * 4 + h];
    float acc = 0.f;
    for (int j = 0; j < deg; ++j) {
        int s = csr_src[row0 + j];
        float l = a_s[s * 4 + h] + ad;
        l = l > 0.f ? l : 0.2f * l;
        float c = expf(l - md) * inv;
        acc += c * xp[(long)s * 256 + t];
    }
    float v = acc + bias[t];
    hout[(long)d * 256 + t] = v > 0.f ? v : expm1f(v);
}

// layer 2: 8 nodes per block, 32 lanes per node; fused bias + row softmax
__global__ __launch_bounds__(256) void agg2_softmax(const int* __restrict__ rowptr,
        const int* __restrict__ csr_src, const float* __restrict__ a_s,
        const float* __restrict__ a_d, const float* __restrict__ m2,
        const float* __restrict__ is2, const float* __restrict__ xp,
        const float* __restrict__ bias, float* __restrict__ out, int N) {
    int t = threadIdx.x;
    int d = blockIdx.x * 8 + (t >> 5);
    if (d >= N) return;
    int c = t & 31;
    int row0 = rowptr[d];
    int deg = rowptr[d + 1] - row0;
    float ad = a_d[d];
    float md = m2[d];
    float inv = is2[d];
    float acc = 0.f;
    for (int j = 0; j < deg; ++j) {
        int s = csr_src[row0 + j];
        float l = a_s[s] + ad;
        l = l > 0.f ? l : 0.2f * l;
        float co = expf(l - md) * inv;
        acc += co * xp[(long)s * 32 + c];
    }
    float v = acc + bias[c];
    float mx = v;
    #pragma unroll
    for (int off = 16; off; off >>= 1) mx = fmaxf(mx, __shfl_xor(mx, off, 32));
    float ex = expf(v - mx);
    float sm = ex;
    #pragma unroll
    for (int off = 16; off; off >>= 1) sm += __shfl_xor(sm, off, 32);
    out[(long)d * 32 + c] = ex / sm;
}

// ---------- host ----------
extern "C" void kernel_launch(void* const* d_in, const int* in_sizes, int n_in,
                              void* d_out, int out_size, void* d_ws, size_t ws_size,
                              hipStream_t stream) {
    const float* x   = (const float*)d_in[0];
    const int*   ei  = (const int*)d_in[1];
    const float* W1  = (const float*)d_in[2];
    const float* as1 = (const float*)d_in[3];
    const float* ad1 = (const float*)d_in[4];
    const float* b1  = (const float*)d_in[5];
    const float* W2  = (const float*)d_in[6];
    const float* as2 = (const float*)d_in[7];
    const float* ad2 = (const float*)d_in[8];
    const float* b2  = (const float*)d_in[9];
    float* out = (float*)d_out;

    const int N = in_sizes[0] / 128;     // 50000
    const int E = in_sizes[1] / 2;       // 640000
    const int Etot = E + N;              // + self loops

    // workspace layout
    float* ws = (float*)d_ws;
    float* xp1  = ws;                        // N*256
    float* h    = xp1 + (long)N * 256;       // N*256
    float* a_s1 = h + (long)N * 256;         // N*4
    float* a_d1 = a_s1 + N * 4;              // N*4
    float* m1   = a_d1 + N * 4;              // N*4
    float* is1  = m1 + N * 4;                // N*4
    float* a_s2 = is1 + N * 4;               // N
    float* a_d2 = a_s2 + N;                  // N
    float* m2   = a_d2 + N;                  // N
    float* is2  = m2 + N;                    // N
    int* deg     = (int*)(is2 + N);          // N
    int* rowptr  = deg + N;                  // N+1
    int* cursor  = rowptr + N + 1;           // N
    int* csr_src = cursor + N;               // Etot
    float* xp2   = xp1;                      // reuse (xp1 dead after layer-1 agg)

    hipMemsetAsync(deg, 0, (size_t)N * sizeof(int), stream);

    // ---- CSR build (shared by both layers) ----
    int nbE = (Etot + 255) / 256;
    count_deg<<<nbE, 256, 0, stream>>>(ei, E, Etot, deg);
    scan_deg<<<1, 1024, 0, stream>>>(deg, rowptr, cursor, N);
    scatter_edges<<<nbE, 256, 0, stream>>>(ei, E, Etot, cursor, csr_src);

    // ---- layer 1 ----
    {
        dim3 g(256 / 64, (N + 63) / 64);
        gemm_f32<64, 64, 16><<<g, 256, 0, stream>>>(x, W1, xp1, N, 256, 128);
    }
    att_proj_h4<<<N, 256, 0, stream>>>(xp1, as1, ad1, a_s1, a_d1, N);
    stats_h4<<<(N + 3) / 4, 256, 0, stream>>>(rowptr, csr_src, a_s1, a_d1, m1, is1, N);
    agg1_gather<<<N, 256, 0, stream>>>(rowptr, csr_src, a_s1, a_d1, m1, is1,
                                       xp1, b1, h, N);

    // ---- layer 2 ----
    {
        dim3 g(1, (N + 63) / 64);
        gemm_f32<64, 64, 16><<<g, 256, 0, stream>>>(h, W2, xp2, N, 32, 256);
    }
    att_proj_h1<<<(N + 7) / 8, 256, 0, stream>>>(xp2, as2, ad2, a_s2, a_d2, N);
    stats_h1<<<(N + 3) / 4, 256, 0, stream>>>(rowptr, csr_src, a_s2, a_d2, m2, is2, N);
    agg2_softmax<<<(N + 7) / 8, 256, 0, stream>>>(rowptr, csr_src, a_s2, a_d2,
                                                  m2, is2, xp2, b2, out, N);
}

// Round 3
// 544.572 us; speedup vs baseline: 1.8444x; 1.1232x over previous
//
#include <hip/hip_runtime.h>
#include <math.h>

#define NEG_SENT -1e30f

// ---------- generic fp32 tiled GEMM: C[M,N] = A[M,K] @ B[K,N] ----------
template<int BM, int BN, int BK>
__global__ __launch_bounds__(256) void gemm_f32(const float* __restrict__ A,
        const float* __restrict__ B, float* __restrict__ C,
        int M, int N, int K) {
    __shared__ float As[BK][BM + 1];
    __shared__ float Bs[BK][BN + 1];
    int tid = threadIdx.x;
    int tx = tid & 15;   // N dir (16)
    int ty = tid >> 4;   // M dir (16)
    int row0 = blockIdx.y * BM;
    int col0 = blockIdx.x * BN;
    float acc[4][4] = {};
    for (int k0 = 0; k0 < K; k0 += BK) {
        #pragma unroll
        for (int i = 0; i < (BM * BK) / 256; ++i) {
            int idx = tid + i * 256;
            int r = idx / BK, c = idx % BK;
            int gr = row0 + r;
            float v = 0.f;
            if (gr < M) v = A[(long)gr * K + k0 + c];
            As[c][r] = v;
        }
        #pragma unroll
        for (int i = 0; i < (BK * BN) / 256; ++i) {
            int idx = tid + i * 256;
            int r = idx / BN, c = idx % BN;
            int gc = col0 + c;
            float v = 0.f;
            if (gc < N) v = B[(long)(k0 + r) * N + gc];
            Bs[r][c] = v;
        }
        __syncthreads();
        #pragma unroll
        for (int k = 0; k < BK; ++k) {
            float a[4], b[4];
            #pragma unroll
            for (int i = 0; i < 4; ++i) a[i] = As[k][ty * 4 + i];
            #pragma unroll
            for (int j = 0; j < 4; ++j) b[j] = Bs[k][tx * 4 + j];
            #pragma unroll
            for (int i = 0; i < 4; ++i)
                #pragma unroll
                for (int j = 0; j < 4; ++j)
                    acc[i][j] += a[i] * b[j];
        }
        __syncthreads();
    }
    #pragma unroll
    for (int i = 0; i < 4; ++i) {
        int gr = row0 + ty * 4 + i;
        if (gr >= M) continue;
        #pragma unroll
        for (int j = 0; j < 4; ++j) {
            int gc = col0 + tx * 4 + j;
            if (gc < N) C[(long)gr * N + gc] = acc[i][j];
        }
    }
}

// ---------- attention projections ----------
__global__ __launch_bounds__(256) void att_proj_h4(const float* __restrict__ xp,
        const float* __restrict__ att_s, const float* __restrict__ att_d,
        float* __restrict__ a_s, float* __restrict__ a_d, int N) {
    int n = blockIdx.x;
    int t = threadIdx.x;
    float p = xp[(long)n * 256 + t];
    float vs = p * att_s[t];
    float vd = p * att_d[t];
    #pragma unroll
    for (int off = 32; off; off >>= 1) {
        vs += __shfl_down(vs, off);
        vd += __shfl_down(vd, off);
    }
    if ((t & 63) == 0) {
        int h = t >> 6;
        a_s[n * 4 + h] = vs;
        a_d[n * 4 + h] = vd;
    }
}

__global__ __launch_bounds__(256) void att_proj_h1(const float* __restrict__ xp,
        const float* __restrict__ att_s, const float* __restrict__ att_d,
        float* __restrict__ a_s, float* __restrict__ a_d, int N) {
    int t = threadIdx.x;
    int n = blockIdx.x * 8 + (t >> 5);
    if (n >= N) return;
    int c = t & 31;
    float p = xp[(long)n * 32 + c];
    float vs = p * att_s[c];
    float vd = p * att_d[c];
    #pragma unroll
    for (int off = 16; off; off >>= 1) {
        vs += __shfl_xor(vs, off, 32);
        vd += __shfl_xor(vd, off, 32);
    }
    if (c == 0) { a_s[n] = vs; a_d[n] = vd; }
}

// ---------- CSR build ----------
__global__ __launch_bounds__(256) void count_deg(const int* __restrict__ ei,
        int E, int Etot, int* __restrict__ deg) {
    int e = blockIdx.x * 256 + threadIdx.x;
    if (e >= Etot) return;
    int d = (e < E) ? ei[E + e] : e - E;
    atomicAdd(&deg[d], 1);
}

__global__ __launch_bounds__(1024) void scan_deg(const int* __restrict__ deg,
        int* __restrict__ rowptr, int* __restrict__ cursor, int N) {
    __shared__ int part[1024];
    int t = threadIdx.x;
    int chunk = (N + 1023) / 1024;
    int lo = t * chunk;
    int hi = lo + chunk; if (hi > N) hi = N; if (lo > N) lo = N;
    int sum = 0;
    for (int i = lo; i < hi; ++i) sum += deg[i];
    part[t] = sum;
    __syncthreads();
    for (int off = 1; off < 1024; off <<= 1) {
        int v = (t >= off) ? part[t - off] : 0;
        __syncthreads();
        part[t] += v;
        __syncthreads();
    }
    int run = (t > 0) ? part[t - 1] : 0;
    for (int i = lo; i < hi; ++i) {
        rowptr[i] = run;
        cursor[i] = run;
        run += deg[i];
    }
    if (t == 1023) rowptr[N] = part[1023];
}

__global__ __launch_bounds__(256) void scatter_edges(const int* __restrict__ ei,
        int E, int Etot, int* __restrict__ cursor, int* __restrict__ csr_src) {
    int e = blockIdx.x * 256 + threadIdx.x;
    if (e >= Etot) return;
    int s, d;
    if (e < E) { s = ei[e]; d = ei[E + e]; } else { s = e - E; d = s; }
    int pos = atomicAdd(&cursor[d], 1);
    csr_src[pos] = s;
}

// ---------- softmax stats + coefficient precompute (fused, no atomics) ----------
__device__ __forceinline__ void merge_ms(float& m, float& s, float m2, float s2) {
    float mn = fmaxf(m, m2);
    s = s * expf(m - mn) + s2 * expf(m2 - mn);
    m = mn;
}

// H=4: wave per node; lane = j0*4 + h. Writes coeff[slot*4+h] in CSR order.
__global__ __launch_bounds__(256) void stats_coeff_h4(const int* __restrict__ rowptr,
        const int* __restrict__ csr_src, const float* __restrict__ a_s,
        const float* __restrict__ a_d, float* __restrict__ coeff, int N) {
    int t = threadIdx.x;
    int d = blockIdx.x * 4 + (t >> 6);
    if (d >= N) return;
    int lane = t & 63;
    int h = lane & 3;
    int j0 = lane >> 2;
    int row0 = rowptr[d];
    int deg = rowptr[d + 1] - row0;
    float ad = a_d[d * 4 + h];
    float m = NEG_SENT, s = 0.f;
    for (int j = j0; j < deg; j += 16) {
        int sn = csr_src[row0 + j];
        float l = a_s[sn * 4 + h] + ad;
        l = l > 0.f ? l : 0.2f * l;
        float mn = fmaxf(m, l);
        s = s * expf(m - mn) + expf(l - mn);
        m = mn;
    }
    #pragma unroll
    for (int off = 4; off <= 32; off <<= 1) {
        float m2 = __shfl_xor(m, off);
        float s2 = __shfl_xor(s, off);
        merge_ms(m, s, m2, s2);
    }
    // all lanes now hold the (m, s) for their head h
    float inv = 1.f / (s + 1e-16f);
    for (int j = j0; j < deg; j += 16) {
        int sn = csr_src[row0 + j];
        float l = a_s[sn * 4 + h] + ad;
        l = l > 0.f ? l : 0.2f * l;
        coeff[(long)(row0 + j) * 4 + h] = expf(l - m) * inv;
    }
}

// H=1: wave per node; writes coeff[slot]
__global__ __launch_bounds__(256) void stats_coeff_h1(const int* __restrict__ rowptr,
        const int* __restrict__ csr_src, const float* __restrict__ a_s,
        const float* __restrict__ a_d, float* __restrict__ coeff, int N) {
    int t = threadIdx.x;
    int d = blockIdx.x * 4 + (t >> 6);
    if (d >= N) return;
    int lane = t & 63;
    int row0 = rowptr[d];
    int deg = rowptr[d + 1] - row0;
    float ad = a_d[d];
    float m = NEG_SENT, s = 0.f;
    for (int j = lane; j < deg; j += 64) {
        int sn = csr_src[row0 + j];
        float l = a_s[sn] + ad;
        l = l > 0.f ? l : 0.2f * l;
        float mn = fmaxf(m, l);
        s = s * expf(m - mn) + expf(l - mn);
        m = mn;
    }
    #pragma unroll
    for (int off = 1; off <= 32; off <<= 1) {
        float m2 = __shfl_xor(m, off);
        float s2 = __shfl_xor(s, off);
        merge_ms(m, s, m2, s2);
    }
    float inv = 1.f / (s + 1e-16f);
    for (int j = lane; j < deg; j += 64) {
        int sn = csr_src[row0 + j];
        float l = a_s[sn] + ad;
        l = l > 0.f ? l : 0.2f * l;
        coeff[row0 + j] = expf(l - m) * inv;
    }
}

// ---------- gather aggregation (pure gather + FMA) ----------
// layer 1: wave per node, lane = float4 channel group; 4 nodes/block.
// fused bias + ELU.
__global__ __launch_bounds__(256) void agg1_gather(const int* __restrict__ rowptr,
        const int* __restrict__ csr_src, const float* __restrict__ coeff,
        const float4* __restrict__ xp4, const float* __restrict__ bias,
        float4* __restrict__ hout4, int N) {
    int t = threadIdx.x;
    int d = blockIdx.x * 4 + (t >> 6);
    if (d >= N) return;
    int lane = t & 63;
    int hsel = lane >> 4;                 // head = channel_group/16
    int row0 = rowptr[d];
    int deg = rowptr[d + 1] - row0;
    float4 acc = make_float4(0.f, 0.f, 0.f, 0.f);
    for (int j = 0; j < deg; ++j) {
        int s = csr_src[row0 + j];
        float c = coeff[(long)(row0 + j) * 4 + hsel];
        float4 v = xp4[(long)s * 64 + lane];
        acc.x += c * v.x; acc.y += c * v.y;
        acc.z += c * v.z; acc.w += c * v.w;
    }
    float4 b = ((const float4*)bias)[lane];
    float4 o;
    float vx = acc.x + b.x; o.x = vx > 0.f ? vx : expm1f(vx);
    float vy = acc.y + b.y; o.y = vy > 0.f ? vy : expm1f(vy);
    float vz = acc.z + b.z; o.z = vz > 0.f ? vz : expm1f(vz);
    float vw = acc.w + b.w; o.w = vw > 0.f ? vw : expm1f(vw);
    hout4[(long)d * 64 + lane] = o;
}

// layer 2: 8 nodes/block, 32 lanes per node; fused bias + row softmax
__global__ __launch_bounds__(256) void agg2_softmax(const int* __restrict__ rowptr,
        const int* __restrict__ csr_src, const float* __restrict__ coeff,
        const float* __restrict__ xp, const float* __restrict__ bias,
        float* __restrict__ out, int N) {
    int t = threadIdx.x;
    int d = blockIdx.x * 8 + (t >> 5);
    if (d >= N) return;
    int c = t & 31;
    int row0 = rowptr[d];
    int deg = rowptr[d + 1] - row0;
    float acc = 0.f;
    for (int j = 0; j < deg; ++j) {
        int s = csr_src[row0 + j];
        float co = coeff[row0 + j];
        acc += co * xp[(long)s * 32 + c];
    }
    float v = acc + bias[c];
    float mx = v;
    #pragma unroll
    for (int off = 16; off; off >>= 1) mx = fmaxf(mx, __shfl_xor(mx, off, 32));
    float ex = expf(v - mx);
    float sm = ex;
    #pragma unroll
    for (int off = 16; off; off >>= 1) sm += __shfl_xor(sm, off, 32);
    out[(long)d * 32 + c] = ex / sm;
}

// ---------- host ----------
extern "C" void kernel_launch(void* const* d_in, const int* in_sizes, int n_in,
                              void* d_out, int out_size, void* d_ws, size_t ws_size,
                              hipStream_t stream) {
    const float* x   = (const float*)d_in[0];
    const int*   ei  = (const int*)d_in[1];
    const float* W1  = (const float*)d_in[2];
    const float* as1 = (const float*)d_in[3];
    const float* ad1 = (const float*)d_in[4];
    const float* b1  = (const float*)d_in[5];
    const float* W2  = (const float*)d_in[6];
    const float* as2 = (const float*)d_in[7];
    const float* ad2 = (const float*)d_in[8];
    const float* b2  = (const float*)d_in[9];
    float* out = (float*)d_out;

    const int N = in_sizes[0] / 128;     // 50000
    const int E = in_sizes[1] / 2;       // 640000
    const int Etot = E + N;              // + self loops

    // workspace layout
    float* ws = (float*)d_ws;
    float* xp1    = ws;                        // N*256 (reused as xp2)
    float* h      = xp1 + (long)N * 256;       // N*256 (reused as coeff2 after gemm2)
    float* a_s1   = h + (long)N * 256;         // N*4
    float* a_d1   = a_s1 + N * 4;              // N*4
    float* a_s2   = a_d1 + N * 4;              // N
    float* a_d2   = a_s2 + N;                  // N
    float* coeff1 = a_d2 + N;                  // Etot*4
    int* deg      = (int*)(coeff1 + (long)Etot * 4); // N
    int* rowptr   = deg + N;                   // N+1
    int* cursor   = rowptr + N + 1;            // N
    int* csr_src  = cursor + N;                // Etot
    float* xp2    = xp1;                       // xp1 dead after layer-1 agg
    float* coeff2 = h;                         // h dead after gemm2

    hipMemsetAsync(deg, 0, (size_t)N * sizeof(int), stream);

    // ---- CSR build (shared by both layers) ----
    int nbE = (Etot + 255) / 256;
    count_deg<<<nbE, 256, 0, stream>>>(ei, E, Etot, deg);
    scan_deg<<<1, 1024, 0, stream>>>(deg, rowptr, cursor, N);
    scatter_edges<<<nbE, 256, 0, stream>>>(ei, E, Etot, cursor, csr_src);

    // ---- layer 1 ----
    {
        dim3 g(256 / 64, (N + 63) / 64);
        gemm_f32<64, 64, 16><<<g, 256, 0, stream>>>(x, W1, xp1, N, 256, 128);
    }
    att_proj_h4<<<N, 256, 0, stream>>>(xp1, as1, ad1, a_s1, a_d1, N);
    stats_coeff_h4<<<(N + 3) / 4, 256, 0, stream>>>(rowptr, csr_src, a_s1, a_d1,
                                                    coeff1, N);
    agg1_gather<<<(N + 3) / 4, 256, 0, stream>>>(rowptr, csr_src, coeff1,
                                                 (const float4*)xp1, b1,
                                                 (float4*)h, N);

    // ---- layer 2 ----
    {
        dim3 g(1, (N + 63) / 64);
        gemm_f32<64, 64, 16><<<g, 256, 0, stream>>>(h, W2, xp2, N, 32, 256);
    }
    att_proj_h1<<<(N + 7) / 8, 256, 0, stream>>>(xp2, as2, ad2, a_s2, a_d2, N);
    stats_coeff_h1<<<(N + 3) / 4, 256, 0, stream>>>(rowptr, csr_src, a_s2, a_d2,
                                                    coeff2, N);
    agg2_softmax<<<(N + 7) / 8, 256, 0, stream>>>(rowptr, csr_src, coeff2,
                                                  xp2, b2, out, N);
}

// Round 4
// 448.043 us; speedup vs baseline: 2.2417x; 1.2154x over previous
//
#include <hip/hip_runtime.h>
#include <math.h>

#define NEG_SENT -1e30f

// ---------- generic fp32 tiled GEMM: C[M,N] = A[M,K] @ B[K,N] ----------
template<int BM, int BN, int BK>
__global__ __launch_bounds__(256) void gemm_f32(const float* __restrict__ A,
        const float* __restrict__ B, float* __restrict__ C,
        int M, int N, int K) {
    __shared__ float As[BK][BM + 1];
    __shared__ float Bs[BK][BN + 1];
    int tid = threadIdx.x;
    int tx = tid & 15;   // N dir (16)
    int ty = tid >> 4;   // M dir (16)
    int row0 = blockIdx.y * BM;
    int col0 = blockIdx.x * BN;
    float acc[4][4] = {};
    for (int k0 = 0; k0 < K; k0 += BK) {
        #pragma unroll
        for (int i = 0; i < (BM * BK) / 256; ++i) {
            int idx = tid + i * 256;
            int r = idx / BK, c = idx % BK;
            int gr = row0 + r;
            float v = 0.f;
            if (gr < M) v = A[(long)gr * K + k0 + c];
            As[c][r] = v;
        }
        #pragma unroll
        for (int i = 0; i < (BK * BN) / 256; ++i) {
            int idx = tid + i * 256;
            int r = idx / BN, c = idx % BN;
            int gc = col0 + c;
            float v = 0.f;
            if (gc < N) v = B[(long)(k0 + r) * N + gc];
            Bs[r][c] = v;
        }
        __syncthreads();
        #pragma unroll
        for (int k = 0; k < BK; ++k) {
            float a[4], b[4];
            #pragma unroll
            for (int i = 0; i < 4; ++i) a[i] = As[k][ty * 4 + i];
            #pragma unroll
            for (int j = 0; j < 4; ++j) b[j] = Bs[k][tx * 4 + j];
            #pragma unroll
            for (int i = 0; i < 4; ++i)
                #pragma unroll
                for (int j = 0; j < 4; ++j)
                    acc[i][j] += a[i] * b[j];
        }
        __syncthreads();
    }
    #pragma unroll
    for (int i = 0; i < 4; ++i) {
        int gr = row0 + ty * 4 + i;
        if (gr >= M) continue;
        #pragma unroll
        for (int j = 0; j < 4; ++j) {
            int gc = col0 + tx * 4 + j;
            if (gc < N) C[(long)gr * N + gc] = acc[i][j];
        }
    }
}

// ---------- attention projections ----------
__global__ __launch_bounds__(256) void att_proj_h4(const float* __restrict__ xp,
        const float* __restrict__ att_s, const float* __restrict__ att_d,
        float* __restrict__ a_s, float* __restrict__ a_d, int N) {
    int n = blockIdx.x;
    int t = threadIdx.x;
    float p = xp[(long)n * 256 + t];
    float vs = p * att_s[t];
    float vd = p * att_d[t];
    #pragma unroll
    for (int off = 32; off; off >>= 1) {
        vs += __shfl_down(vs, off);
        vd += __shfl_down(vd, off);
    }
    if ((t & 63) == 0) {
        int h = t >> 6;
        a_s[n * 4 + h] = vs;
        a_d[n * 4 + h] = vd;
    }
}

__global__ __launch_bounds__(256) void att_proj_h1(const float* __restrict__ xp,
        const float* __restrict__ att_s, const float* __restrict__ att_d,
        float* __restrict__ a_s, float* __restrict__ a_d, int N) {
    int t = threadIdx.x;
    int n = blockIdx.x * 8 + (t >> 5);
    if (n >= N) return;
    int c = t & 31;
    float p = xp[(long)n * 32 + c];
    float vs = p * att_s[c];
    float vd = p * att_d[c];
    #pragma unroll
    for (int off = 16; off; off >>= 1) {
        vs += __shfl_xor(vs, off, 32);
        vd += __shfl_xor(vd, off, 32);
    }
    if (c == 0) { a_s[n] = vs; a_d[n] = vd; }
}

// ---------- CSR build ----------
__global__ __launch_bounds__(256) void count_deg(const int* __restrict__ ei,
        int E, int Etot, int* __restrict__ deg) {
    int e = blockIdx.x * 256 + threadIdx.x;
    if (e >= Etot) return;
    int d = (e < E) ? ei[E + e] : e - E;
    atomicAdd(&deg[d], 1);
}

// hierarchical exclusive scan: 1024 elems per block
__global__ __launch_bounds__(256) void scan_local(const int* __restrict__ deg,
        int* __restrict__ rowptr, int* __restrict__ blocksum, int N) {
    __shared__ int part[256];
    int b = blockIdx.x, t = threadIdx.x;
    int base = b * 1024 + t * 4;
    int4 v = make_int4(0, 0, 0, 0);
    if (base + 3 < N) {
        v = *(const int4*)(deg + base);
    } else {
        if (base + 0 < N) v.x = deg[base + 0];
        if (base + 1 < N) v.y = deg[base + 1];
        if (base + 2 < N) v.z = deg[base + 2];
        if (base + 3 < N) v.w = deg[base + 3];
    }
    part[t] = v.x + v.y + v.z + v.w;
    __syncthreads();
    #pragma unroll
    for (int off = 1; off < 256; off <<= 1) {
        int val = (t >= off) ? part[t - off] : 0;
        __syncthreads();
        part[t] += val;
        __syncthreads();
    }
    if (t == 255) blocksum[b] = part[255];
    int r0 = (t > 0) ? part[t - 1] : 0;
    int r1 = r0 + v.x;
    int r2 = r1 + v.y;
    int r3 = r2 + v.z;
    if (base + 3 < N) {
        *(int4*)(rowptr + base) = make_int4(r0, r1, r2, r3);
    } else {
        if (base + 0 < N) rowptr[base + 0] = r0;
        if (base + 1 < N) rowptr[base + 1] = r1;
        if (base + 2 < N) rowptr[base + 2] = r2;
        if (base + 3 < N) rowptr[base + 3] = r3;
    }
}

__global__ __launch_bounds__(256) void scan_block_sums(const int* __restrict__ blocksum,
        int* __restrict__ blockoff, int nb) {
    __shared__ int part[256];
    int t = threadIdx.x;
    part[t] = (t < nb) ? blocksum[t] : 0;
    __syncthreads();
    #pragma unroll
    for (int off = 1; off < 256; off <<= 1) {
        int val = (t >= off) ? part[t - off] : 0;
        __syncthreads();
        part[t] += val;
        __syncthreads();
    }
    if (t < nb) blockoff[t] = (t > 0) ? part[t - 1] : 0;
}

__global__ __launch_bounds__(256) void scan_add(int* __restrict__ rowptr,
        const int* __restrict__ blockoff, int* __restrict__ cursor,
        int N, int Etot) {
    int b = blockIdx.x, t = threadIdx.x;
    int base = b * 1024 + t * 4;
    int off = blockoff[b];
    if (base + 3 < N) {
        int4 v = *(const int4*)(rowptr + base);
        v.x += off; v.y += off; v.z += off; v.w += off;
        *(int4*)(rowptr + base) = v;
        *(int4*)(cursor + base) = v;
    } else {
        for (int i = 0; i < 4; ++i) {
            if (base + i < N) {
                int v = rowptr[base + i] + off;
                rowptr[base + i] = v;
                cursor[base + i] = v;
            }
        }
    }
    if (b == 0 && t == 0) rowptr[N] = Etot;
}

__global__ __launch_bounds__(256) void scatter_edges(const int* __restrict__ ei,
        int E, int Etot, int* __restrict__ cursor, int* __restrict__ csr_src) {
    int e = blockIdx.x * 256 + threadIdx.x;
    if (e >= Etot) return;
    int s, d;
    if (e < E) { s = ei[e]; d = ei[E + e]; } else { s = e - E; d = s; }
    int pos = atomicAdd(&cursor[d], 1);
    csr_src[pos] = s;
}

// ---------- softmax stats + coefficient precompute (fused, no atomics) ----------
__device__ __forceinline__ void merge_ms(float& m, float& s, float m2, float s2) {
    float mn = fmaxf(m, m2);
    s = s * expf(m - mn) + s2 * expf(m2 - mn);
    m = mn;
}

// H=4: wave per node; lane = j0*4 + h. Writes coeff[slot*4+h] in CSR order.
__global__ __launch_bounds__(256) void stats_coeff_h4(const int* __restrict__ rowptr,
        const int* __restrict__ csr_src, const float* __restrict__ a_s,
        const float* __restrict__ a_d, float* __restrict__ coeff, int N) {
    int t = threadIdx.x;
    int d = blockIdx.x * 4 + (t >> 6);
    if (d >= N) return;
    int lane = t & 63;
    int h = lane & 3;
    int j0 = lane >> 2;
    int row0 = rowptr[d];
    int deg = rowptr[d + 1] - row0;
    float ad = a_d[d * 4 + h];
    float m = NEG_SENT, s = 0.f;
    for (int j = j0; j < deg; j += 16) {
        int sn = csr_src[row0 + j];
        float l = a_s[sn * 4 + h] + ad;
        l = l > 0.f ? l : 0.2f * l;
        float mn = fmaxf(m, l);
        s = s * expf(m - mn) + expf(l - mn);
        m = mn;
    }
    #pragma unroll
    for (int off = 4; off <= 32; off <<= 1) {
        float m2 = __shfl_xor(m, off);
        float s2 = __shfl_xor(s, off);
        merge_ms(m, s, m2, s2);
    }
    float inv = 1.f / (s + 1e-16f);
    for (int j = j0; j < deg; j += 16) {
        int sn = csr_src[row0 + j];
        float l = a_s[sn * 4 + h] + ad;
        l = l > 0.f ? l : 0.2f * l;
        coeff[(long)(row0 + j) * 4 + h] = expf(l - m) * inv;
    }
}

// H=1: wave per node; writes coeff[slot]
__global__ __launch_bounds__(256) void stats_coeff_h1(const int* __restrict__ rowptr,
        const int* __restrict__ csr_src, const float* __restrict__ a_s,
        const float* __restrict__ a_d, float* __restrict__ coeff, int N) {
    int t = threadIdx.x;
    int d = blockIdx.x * 4 + (t >> 6);
    if (d >= N) return;
    int lane = t & 63;
    int row0 = rowptr[d];
    int deg = rowptr[d + 1] - row0;
    float ad = a_d[d];
    float m = NEG_SENT, s = 0.f;
    for (int j = lane; j < deg; j += 64) {
        int sn = csr_src[row0 + j];
        float l = a_s[sn] + ad;
        l = l > 0.f ? l : 0.2f * l;
        float mn = fmaxf(m, l);
        s = s * expf(m - mn) + expf(l - mn);
        m = mn;
    }
    #pragma unroll
    for (int off = 1; off <= 32; off <<= 1) {
        float m2 = __shfl_xor(m, off);
        float s2 = __shfl_xor(s, off);
        merge_ms(m, s, m2, s2);
    }
    float inv = 1.f / (s + 1e-16f);
    for (int j = lane; j < deg; j += 64) {
        int sn = csr_src[row0 + j];
        float l = a_s[sn] + ad;
        l = l > 0.f ? l : 0.2f * l;
        coeff[row0 + j] = expf(l - m) * inv;
    }
}

// ---------- gather aggregation (pure gather + FMA) ----------
// layer 1: wave per node, lane = float4 channel group; 4 nodes/block.
__global__ __launch_bounds__(256) void agg1_gather(const int* __restrict__ rowptr,
        const int* __restrict__ csr_src, const float* __restrict__ coeff,
        const float4* __restrict__ xp4, const float* __restrict__ bias,
        float4* __restrict__ hout4, int N) {
    int t = threadIdx.x;
    int d = blockIdx.x * 4 + (t >> 6);
    if (d >= N) return;
    int lane = t & 63;
    int hsel = lane >> 4;                 // head = channel_group/16
    int row0 = rowptr[d];
    int deg = rowptr[d + 1] - row0;
    float4 acc = make_float4(0.f, 0.f, 0.f, 0.f);
    for (int j = 0; j < deg; ++j) {
        int s = csr_src[row0 + j];
        float c = coeff[(long)(row0 + j) * 4 + hsel];
        float4 v = xp4[(long)s * 64 + lane];
        acc.x += c * v.x; acc.y += c * v.y;
        acc.z += c * v.z; acc.w += c * v.w;
    }
    float4 b = ((const float4*)bias)[lane];
    float4 o;
    float vx = acc.x + b.x; o.x = vx > 0.f ? vx : expm1f(vx);
    float vy = acc.y + b.y; o.y = vy > 0.f ? vy : expm1f(vy);
    float vz = acc.z + b.z; o.z = vz > 0.f ? vz : expm1f(vz);
    float vw = acc.w + b.w; o.w = vw > 0.f ? vw : expm1f(vw);
    hout4[(long)d * 64 + lane] = o;
}

// layer 2: 8 nodes/block, 32 lanes per node; fused bias + row softmax
__global__ __launch_bounds__(256) void agg2_softmax(const int* __restrict__ rowptr,
        const int* __restrict__ csr_src, const float* __restrict__ coeff,
        const float* __restrict__ xp, const float* __restrict__ bias,
        float* __restrict__ out, int N) {
    int t = threadIdx.x;
    int d = blockIdx.x * 8 + (t >> 5);
    if (d >= N) return;
    int c = t & 31;
    int row0 = rowptr[d];
    int deg = rowptr[d + 1] - row0;
    float acc = 0.f;
    for (int j = 0; j < deg; ++j) {
        int s = csr_src[row0 + j];
        float co = coeff[row0 + j];
        acc += co * xp[(long)s * 32 + c];
    }
    float v = acc + bias[c];
    float mx = v;
    #pragma unroll
    for (int off = 16; off; off >>= 1) mx = fmaxf(mx, __shfl_xor(mx, off, 32));
    float ex = expf(v - mx);
    float sm = ex;
    #pragma unroll
    for (int off = 16; off; off >>= 1) sm += __shfl_xor(sm, off, 32);
    out[(long)d * 32 + c] = ex / sm;
}

// ---------- host ----------
extern "C" void kernel_launch(void* const* d_in, const int* in_sizes, int n_in,
                              void* d_out, int out_size, void* d_ws, size_t ws_size,
                              hipStream_t stream) {
    const float* x   = (const float*)d_in[0];
    const int*   ei  = (const int*)d_in[1];
    const float* W1  = (const float*)d_in[2];
    const float* as1 = (const float*)d_in[3];
    const float* ad1 = (const float*)d_in[4];
    const float* b1  = (const float*)d_in[5];
    const float* W2  = (const float*)d_in[6];
    const float* as2 = (const float*)d_in[7];
    const float* ad2 = (const float*)d_in[8];
    const float* b2  = (const float*)d_in[9];
    float* out = (float*)d_out;

    const int N = in_sizes[0] / 128;     // 50000
    const int E = in_sizes[1] / 2;       // 640000
    const int Etot = E + N;              // + self loops

    // workspace layout (all offsets kept 16B-aligned)
    float* ws = (float*)d_ws;
    float* xp1    = ws;                        // N*256 (reused as xp2)
    float* h      = xp1 + (long)N * 256;       // N*256 (reused as coeff2)
    float* a_s1   = h + (long)N * 256;         // N*4
    float* a_d1   = a_s1 + N * 4;              // N*4
    float* a_s2   = a_d1 + N * 4;              // N
    float* a_d2   = a_s2 + N;                  // N
    float* coeff1 = a_d2 + N;                  // Etot*4
    int* deg      = (int*)(coeff1 + (long)Etot * 4); // N
    int* rowptr   = deg + N;                   // N+4 (pad to keep alignment)
    int* cursor   = rowptr + N + 4;            // N
    int* csr_src  = cursor + N;                // Etot
    int* blocksum = csr_src + Etot;            // 256
    int* blockoff = blocksum + 256;            // 256
    float* xp2    = xp1;                       // xp1 dead after layer-1 agg
    float* coeff2 = h;                         // h dead after gemm2

    hipMemsetAsync(deg, 0, (size_t)N * sizeof(int), stream);

    // ---- CSR build (shared by both layers) ----
    int nbE = (Etot + 255) / 256;
    int nbS = (N + 1023) / 1024;
    count_deg<<<nbE, 256, 0, stream>>>(ei, E, Etot, deg);
    scan_local<<<nbS, 256, 0, stream>>>(deg, rowptr, blocksum, N);
    scan_block_sums<<<1, 256, 0, stream>>>(blocksum, blockoff, nbS);
    scan_add<<<nbS, 256, 0, stream>>>(rowptr, blockoff, cursor, N, Etot);
    scatter_edges<<<nbE, 256, 0, stream>>>(ei, E, Etot, cursor, csr_src);

    // ---- layer 1 ----
    {
        dim3 g(256 / 64, (N + 63) / 64);
        gemm_f32<64, 64, 16><<<g, 256, 0, stream>>>(x, W1, xp1, N, 256, 128);
    }
    att_proj_h4<<<N, 256, 0, stream>>>(xp1, as1, ad1, a_s1, a_d1, N);
    stats_coeff_h4<<<(N + 3) / 4, 256, 0, stream>>>(rowptr, csr_src, a_s1, a_d1,
                                                    coeff1, N);
    agg1_gather<<<(N + 3) / 4, 256, 0, stream>>>(rowptr, csr_src, coeff1,
                                                 (const float4*)xp1, b1,
                                                 (float4*)h, N);

    // ---- layer 2 ----
    {
        dim3 g(1, (N + 63) / 64);
        gemm_f32<64, 64, 16><<<g, 256, 0, stream>>>(h, W2, xp2, N, 32, 256);
    }
    att_proj_h1<<<(N + 7) / 8, 256, 0, stream>>>(xp2, as2, ad2, a_s2, a_d2, N);
    stats_coeff_h1<<<(N + 3) / 4, 256, 0, stream>>>(rowptr, csr_src, a_s2, a_d2,
                                                    coeff2, N);
    agg2_softmax<<<(N + 7) / 8, 256, 0, stream>>>(rowptr, csr_src, coeff2,
                                                  xp2, b2, out, N);
}